// Round 4
// baseline (388.604 us; speedup 1.0000x reference)
//
#include <hip/hip_runtime.h>

// Siamese GeoCheby, round 4: dense-L MFMA design, 7 dispatches.
//  - L_hat materialized dense fp32 per graph (268x268), built by global atomicAdd
//    scatter (handles duplicate edges); no CSR, no LDS gather chains.
//  - conv1: h = relu(xw0 + L@xw1 + b1)  [MFMA], epilogue also emits H1 = h@w4_1
//  - conv2: f = h@w4_0 + b4 + L@H1      [MFMA]
//  - fc1: bf16 MFMA split-K8 -> r1p; fc2: fused sum+relu+bias+MFMA+bias -> out
//  - L zero-fill fused into k_prep; r1p aliases L; fb aliases xw0.

#define NN   268
#define EE   8576
#define NG   192
#define FDIM 4288        // 268*16

typedef __bf16 bf16_t;
typedef bf16_t bf16x8 __attribute__((ext_vector_type(8)));
typedef bf16_t bf16x4 __attribute__((ext_vector_type(4)));
typedef float  f32x4  __attribute__((ext_vector_type(4)));

// ---- workspace layout (float32 slots) ----
#define XW0_OFF  0                    // 192*4288 f32; later reused as FB (bf16)
#define XW1B_OFF 823296               // 192*4288 bf16 = 411648 f
#define WB_OFF   1234944              // 1024*4288 bf16 = 2195456 f
#define WB2_OFF  3430400              // 512*1024 bf16 = 262144 f
#define WXT_OFF  3692544              // 4608 f
#define HB_OFF   3697152              // 192*4288 bf16 = 411648 f
#define H1G_OFF  4108800              // 192*4288 bf16 = 411648 f
#define L_OFF    4520448              // 192*268*268 f32 = 13790208 f; later reused as R1P
#define WS_TOP   18310656             // 73.2 MB
#define R1P_OFF  L_OFF                // 8*192*1024 = 1572864 f (L dead after conv2)
#define FB_OFF   XW0_OFF              // 192*4288 bf16 (xw0 dead after conv1)

#define LFLOATS  13790208
#define NCASTB   2144                 // fc1w cast blocks
#define NCASTB2  256                  // fc2w cast blocks
#define LZB      3367                 // L zero blocks (4096 f32 each)

// ---------------------------------------------------------------------------
// K0: cast fc1_w/fc2_w to bf16, zero L, build MFMA B-frags of [w0|w1]
// ---------------------------------------------------------------------------
__global__ __launch_bounds__(256) void k_prep(
    const float* __restrict__ fc1w, const float* __restrict__ fc2w,
    const float* __restrict__ gc1w,
    bf16_t* __restrict__ wb, bf16_t* __restrict__ wb2,
    float* __restrict__ L, bf16_t* __restrict__ wxt)
{
    const int bx = blockIdx.x;
    if (bx < NCASTB + NCASTB2) {
        const float* src; bf16_t* dst; size_t base;
        if (bx < NCASTB) { src = fc1w; dst = wb;  base = ((size_t)bx * 256 + threadIdx.x) * 8; }
        else             { src = fc2w; dst = wb2; base = ((size_t)(bx - NCASTB) * 256 + threadIdx.x) * 8; }
        const float4 a = *(const float4*)(src + base);
        const float4 b = *(const float4*)(src + base + 4);
        bf16x8 v;
        v[0] = (bf16_t)a.x; v[1] = (bf16_t)a.y; v[2] = (bf16_t)a.z; v[3] = (bf16_t)a.w;
        v[4] = (bf16_t)b.x; v[5] = (bf16_t)b.y; v[6] = (bf16_t)b.z; v[7] = (bf16_t)b.w;
        *(bf16x8*)(dst + base) = v;
    } else if (bx < NCASTB + NCASTB2 + LZB) {
        const size_t i0 = (size_t)(bx - NCASTB - NCASTB2) * 4096 + (size_t)threadIdx.x * 16;
        const float4 z = make_float4(0.f, 0.f, 0.f, 0.f);
        if (i0 + 16 <= LFLOATS) {
            *(float4*)(L + i0)      = z;
            *(float4*)(L + i0 + 4)  = z;
            *(float4*)(L + i0 + 8)  = z;
            *(float4*)(L + i0 + 12) = z;
        }
    } else {
        // B-frag for 16x16x32: lane holds B[k=(lane>>4)*8+j][n=lane&15]
        for (int idx = threadIdx.x; idx < 2 * 9 * 64; idx += 256) {
            const int lane = idx & 63, chunk = (idx >> 6) % 9, nt = idx / (9 * 64);
            const int n = lane & 15, q = lane >> 4;
            bf16x8 v;
#pragma unroll
            for (int j = 0; j < 8; ++j) {
                const int k = chunk * 32 + q * 8 + j;
                v[j] = (k < NN) ? (bf16_t)gc1w[nt * FDIM + k * 16 + n] : (bf16_t)0.f;
            }
            *(bf16x8*)(wxt + (size_t)idx * 8) = v;
        }
    }
}

// ---------------------------------------------------------------------------
// K1: per-graph deg/dis + dense-L scatter (fire-and-forget global atomicAdd)
// ---------------------------------------------------------------------------
__global__ __launch_bounds__(256) void k_lb(
    const int* __restrict__ ei0, const int* __restrict__ ei1, const int* __restrict__ ei2,
    const float* __restrict__ ea0, const float* __restrict__ ea1, const float* __restrict__ ea2,
    float* __restrict__ L)
{
    const int g = blockIdx.x;
    const int br = g >> 6, b = g & 63;
    const int*   ei = (br == 0) ? ei0 : (br == 1) ? ei1 : ei2;
    const float* ea = (br == 0) ? ea0 : (br == 1) ? ea1 : ea2;
    const int*   rowp = ei + (size_t)b * (2 * EE);
    const int*   colp = rowp + EE;
    const float* eap  = ea + (size_t)b * EE;
    __shared__ float degS[NN];
    const int tid = threadIdx.x;

    for (int n = tid; n < NN; n += 256) degS[n] = 0.f;
    __syncthreads();
    for (int e = tid; e < EE; e += 256) atomicAdd(&degS[rowp[e]], eap[e]);
    __syncthreads();
    for (int n = tid; n < NN; n += 256) {
        const float d = degS[n];
        degS[n] = (d > 0.f) ? rsqrtf(d) : 0.f;
    }
    __syncthreads();
    float* Lg = L + (size_t)g * (NN * NN);
    for (int e = tid; e < EE; e += 256) {
        const int r = rowp[e], c = colp[e];
        atomicAdd(&Lg[r * NN + c], -eap[e] * degS[r] * degS[c]);
    }
}

// ---------------------------------------------------------------------------
// K2: xw = x @ [w0|w1] via MFMA (4 waves/block, wave = one 16-row tile)
// ---------------------------------------------------------------------------
__global__ __launch_bounds__(256) void k_xw(
    const float* __restrict__ x0, const float* __restrict__ x1, const float* __restrict__ x2,
    const bf16_t* __restrict__ wxt, float* __restrict__ xw0, bf16_t* __restrict__ xw1b)
{
    const int g = blockIdx.y;
    const int br = g >> 6, b = g & 63;
    const float* x = ((br == 0) ? x0 : (br == 1) ? x1 : x2) + (size_t)b * (NN * NN);
    const int wave = threadIdx.x >> 6, lane = threadIdx.x & 63;
    const int tile = blockIdx.x * 4 + wave;
    if (tile >= 17) return;
    const int q = lane >> 4, nlo = lane & 15;
    const int mrow = tile * 16 + nlo;
    const bool mvalid = (mrow < NN);
    const float* xrow = x + (size_t)mrow * NN;

    f32x4 acc0 = {0.f, 0.f, 0.f, 0.f}, acc1 = {0.f, 0.f, 0.f, 0.f};
    for (int ch = 0; ch < 9; ++ch) {
        const int k0 = ch * 32 + q * 8;
        float4 p0 = make_float4(0.f, 0.f, 0.f, 0.f);
        float4 p1 = make_float4(0.f, 0.f, 0.f, 0.f);
        if (mvalid) {
            if (k0 < NN)     p0 = *(const float4*)(xrow + k0);
            if (k0 + 4 < NN) p1 = *(const float4*)(xrow + k0 + 4);
        }
        bf16x8 a;
        a[0] = (bf16_t)p0.x; a[1] = (bf16_t)p0.y; a[2] = (bf16_t)p0.z; a[3] = (bf16_t)p0.w;
        a[4] = (bf16_t)p1.x; a[5] = (bf16_t)p1.y; a[6] = (bf16_t)p1.z; a[7] = (bf16_t)p1.w;
        const bf16x8 b0 = *(const bf16x8*)(wxt + (size_t)(ch * 64 + lane) * 8);
        const bf16x8 b1 = *(const bf16x8*)(wxt + (size_t)(576 + ch * 64 + lane) * 8);
        acc0 = __builtin_amdgcn_mfma_f32_16x16x32_bf16(a, b0, acc0, 0, 0, 0);
        acc1 = __builtin_amdgcn_mfma_f32_16x16x32_bf16(a, b1, acc1, 0, 0, 0);
    }
    const int col = nlo;
#pragma unroll
    for (int r = 0; r < 4; ++r) {
        const int row = tile * 16 + q * 4 + r;
        if (row < NN) {
            xw0[((size_t)g * NN + row) * 16 + col]  = acc0[r];
            xw1b[((size_t)g * NN + row) * 16 + col] = (bf16_t)acc1[r];
        }
    }
}

// ---------------------------------------------------------------------------
// K3: conv1: h = relu(xw0 + L@xw1 + b1) -> hb; epilogue H1 = h@w4_1 -> h1g
// ---------------------------------------------------------------------------
__global__ __launch_bounds__(256) void k_conv1(
    const float* __restrict__ L, const float* __restrict__ xw0,
    const bf16_t* __restrict__ xw1b, const float* __restrict__ gc1b,
    const float* __restrict__ gc4w, bf16_t* __restrict__ hb, bf16_t* __restrict__ h1g)
{
    const int g = blockIdx.y;
    const int tid = threadIdx.x;
    const int wave = tid >> 6, lane = tid & 63;
    const int tile = blockIdx.x * 4 + wave;
    const int q = lane >> 4, nlo = lane & 15;
    const int blk0 = blockIdx.x * 64;

    __shared__ __align__(16) bf16_t x1_s[NN * 16];      // 8.6 KB
    __shared__ __align__(16) bf16_t frag_s[9 * 64 * 8]; // 9.2 KB
    __shared__ float h_s[64 * 17];                      // 4.3 KB, stride 17
    __shared__ float w41_s[256];
    __shared__ float b1_s[16];

    {
        const bf16x8* src = (const bf16x8*)(xw1b + (size_t)g * FDIM);
        for (int i = tid; i < FDIM / 8; i += 256) ((bf16x8*)x1_s)[i] = src[i];
    }
    if (tid < 256) w41_s[tid] = gc4w[256 + tid];
    if (tid < 16) b1_s[tid] = gc1b[tid];
    __syncthreads();
    for (int it = tid; it < 576; it += 256) {
        const int fl = it & 63, ch = it >> 6;
        const int fn = fl & 15, fq = fl >> 4;
        bf16x8 v;
#pragma unroll
        for (int j = 0; j < 8; ++j) {
            const int k = ch * 32 + fq * 8 + j;
            v[j] = (k < NN) ? x1_s[k * 16 + fn] : (bf16_t)0.f;
        }
        *(bf16x8*)(frag_s + (size_t)it * 8) = v;
    }
    __syncthreads();

    if (tile < 17) {
        const int m = tile * 16 + nlo;
        const bool mv = (m < NN);
        const float* lrow = L + ((size_t)g * NN + m) * NN;
        f32x4 acc = {0.f, 0.f, 0.f, 0.f};
        for (int ch = 0; ch < 9; ++ch) {
            const int k0 = ch * 32 + q * 8;
            float4 p0 = make_float4(0.f, 0.f, 0.f, 0.f);
            float4 p1 = make_float4(0.f, 0.f, 0.f, 0.f);
            if (mv) {
                if (k0 < NN)     p0 = *(const float4*)(lrow + k0);
                if (k0 + 4 < NN) p1 = *(const float4*)(lrow + k0 + 4);
            }
            bf16x8 a;
            a[0] = (bf16_t)p0.x; a[1] = (bf16_t)p0.y; a[2] = (bf16_t)p0.z; a[3] = (bf16_t)p0.w;
            a[4] = (bf16_t)p1.x; a[5] = (bf16_t)p1.y; a[6] = (bf16_t)p1.z; a[7] = (bf16_t)p1.w;
            const bf16x8 bv = *(const bf16x8*)(frag_s + (size_t)(ch * 64 + lane) * 8);
            acc = __builtin_amdgcn_mfma_f32_16x16x32_bf16(a, bv, acc, 0, 0, 0);
        }
#pragma unroll
        for (int r = 0; r < 4; ++r) {
            const int row = tile * 16 + q * 4 + r;
            if (row < NN) {
                float v = acc[r] + xw0[((size_t)g * NN + row) * 16 + nlo] + b1_s[nlo];
                v = fmaxf(v, 0.f);
                hb[((size_t)g * NN + row) * 16 + nlo] = (bf16_t)v;
                h_s[(row - blk0) * 17 + nlo] = v;
            }
        }
    }
    __syncthreads();

    // H1 = h @ w4[1] for this block's 64 rows
    {
        const int m = tid >> 2, jb = tid & 3;
        const int row = blk0 + m;
        if (row < NN) {
            float4 a = make_float4(0.f, 0.f, 0.f, 0.f);
#pragma unroll
            for (int k = 0; k < 16; ++k) {
                const float hv = h_s[m * 17 + k];
                const float4 w = *(const float4*)&w41_s[k * 16 + jb * 4];
                a.x += hv * w.x; a.y += hv * w.y; a.z += hv * w.z; a.w += hv * w.w;
            }
            bf16x4 o;
            o[0] = (bf16_t)a.x; o[1] = (bf16_t)a.y; o[2] = (bf16_t)a.z; o[3] = (bf16_t)a.w;
            *(bf16x4*)(h1g + ((size_t)g * NN + row) * 16 + jb * 4) = o;
        }
    }
}

// ---------------------------------------------------------------------------
// K4: conv2: f = h@w4_0 + b4 + L@H1 -> fb (bf16)
// ---------------------------------------------------------------------------
__global__ __launch_bounds__(256) void k_conv2(
    const float* __restrict__ L, const bf16_t* __restrict__ hb,
    const bf16_t* __restrict__ h1g, const float* __restrict__ gc4w,
    const float* __restrict__ gc4b, bf16_t* __restrict__ fb)
{
    const int g = blockIdx.y;
    const int tid = threadIdx.x;
    const int wave = tid >> 6, lane = tid & 63;
    const int tile = blockIdx.x * 4 + wave;
    const int q = lane >> 4, nlo = lane & 15;

    __shared__ __align__(16) bf16_t h1_s[NN * 16];
    __shared__ __align__(16) bf16_t frag_s[9 * 64 * 8];
    __shared__ float w40_s[256];
    __shared__ float b4_s[16];

    {
        const bf16x8* src = (const bf16x8*)(h1g + (size_t)g * FDIM);
        for (int i = tid; i < FDIM / 8; i += 256) ((bf16x8*)h1_s)[i] = src[i];
    }
    if (tid < 256) w40_s[tid] = gc4w[tid];
    if (tid < 16) b4_s[tid] = gc4b[tid];
    __syncthreads();
    for (int it = tid; it < 576; it += 256) {
        const int fl = it & 63, ch = it >> 6;
        const int fn = fl & 15, fq = fl >> 4;
        bf16x8 v;
#pragma unroll
        for (int j = 0; j < 8; ++j) {
            const int k = ch * 32 + fq * 8 + j;
            v[j] = (k < NN) ? h1_s[k * 16 + fn] : (bf16_t)0.f;
        }
        *(bf16x8*)(frag_s + (size_t)it * 8) = v;
    }
    __syncthreads();

    if (tile >= 17) return;
    const int m = tile * 16 + nlo;
    const bool mv = (m < NN);
    const float* lrow = L + ((size_t)g * NN + m) * NN;
    f32x4 acc = {0.f, 0.f, 0.f, 0.f};
    for (int ch = 0; ch < 9; ++ch) {
        const int k0 = ch * 32 + q * 8;
        float4 p0 = make_float4(0.f, 0.f, 0.f, 0.f);
        float4 p1 = make_float4(0.f, 0.f, 0.f, 0.f);
        if (mv) {
            if (k0 < NN)     p0 = *(const float4*)(lrow + k0);
            if (k0 + 4 < NN) p1 = *(const float4*)(lrow + k0 + 4);
        }
        bf16x8 a;
        a[0] = (bf16_t)p0.x; a[1] = (bf16_t)p0.y; a[2] = (bf16_t)p0.z; a[3] = (bf16_t)p0.w;
        a[4] = (bf16_t)p1.x; a[5] = (bf16_t)p1.y; a[6] = (bf16_t)p1.z; a[7] = (bf16_t)p1.w;
        const bf16x8 bv = *(const bf16x8*)(frag_s + (size_t)(ch * 64 + lane) * 8);
        acc = __builtin_amdgcn_mfma_f32_16x16x32_bf16(a, bv, acc, 0, 0, 0);
    }
    // epilogue: + h@w4_0 + b4
    float w40col[16];
#pragma unroll
    for (int k = 0; k < 16; ++k) w40col[k] = w40_s[k * 16 + nlo];
#pragma unroll
    for (int r = 0; r < 4; ++r) {
        const int row = tile * 16 + q * 4 + r;
        if (row < NN) {
            const bf16x8 h0 = *(const bf16x8*)(hb + ((size_t)g * NN + row) * 16);
            const bf16x8 h1 = *(const bf16x8*)(hb + ((size_t)g * NN + row) * 16 + 8);
            float s = acc[r] + b4_s[nlo];
#pragma unroll
            for (int k = 0; k < 8; ++k) s += (float)h0[k] * w40col[k];
#pragma unroll
            for (int k = 0; k < 8; ++k) s += (float)h1[k] * w40col[8 + k];
            fb[((size_t)g * NN + row) * 16 + nlo] = (bf16_t)s;
        }
    }
}

// ---------------------------------------------------------------------------
// K5: fc1 MFMA split-K8: r1p[kz][192][1024] = fb @ wb^T
// ---------------------------------------------------------------------------
__global__ __launch_bounds__(256) void k_fc1(
    const bf16_t* __restrict__ fb, const bf16_t* __restrict__ wb, float* __restrict__ r1p)
{
    const int mt = blockIdx.x, nb = blockIdx.y, kz = blockIdx.z;
    const int wid = threadIdx.x >> 6, lane = threadIdx.x & 63;
    const int q = lane >> 4, nlo = lane & 15;
    const int n0 = nb * 256 + wid * 64;
    const int cstart = (kz < 6) ? kz * 17 : 102 + (kz - 6) * 16;
    const int ccnt   = (kz < 6) ? 17 : 16;

    const bf16_t* arow = fb + (size_t)(mt * 16 + nlo) * FDIM + q * 8;
    const bf16_t* brow = wb + (size_t)(n0 + nlo) * FDIM + q * 8;
    f32x4 acc[4];
#pragma unroll
    for (int t = 0; t < 4; ++t) { acc[t][0]=0.f; acc[t][1]=0.f; acc[t][2]=0.f; acc[t][3]=0.f; }

    for (int ch = 0; ch < ccnt; ++ch) {
        const size_t ko = (size_t)(cstart + ch) * 32;
        const bf16x8 a = *(const bf16x8*)(arow + ko);
#pragma unroll
        for (int t = 0; t < 4; ++t) {
            const bf16x8 bv = *(const bf16x8*)(brow + (size_t)t * 16 * FDIM + ko);
            acc[t] = __builtin_amdgcn_mfma_f32_16x16x32_bf16(a, bv, acc[t], 0, 0, 0);
        }
    }
    float* outp = r1p + (size_t)kz * (NG * 1024);
#pragma unroll
    for (int t = 0; t < 4; ++t)
#pragma unroll
        for (int r = 0; r < 4; ++r)
            outp[(size_t)(mt * 16 + q * 4 + r) * 1024 + n0 + t * 16 + nlo] = acc[t][r];
}

// ---------------------------------------------------------------------------
// K6: fc2 fused: out = relu(sum_kz r1p + fc1_b) @ wb2^T + fc2_b
// ---------------------------------------------------------------------------
__global__ __launch_bounds__(256) void k_fc2(
    const float* __restrict__ r1p, const float* __restrict__ b1,
    const bf16_t* __restrict__ wb2, const float* __restrict__ b2,
    float* __restrict__ out)
{
    const int mt = blockIdx.x;
    const int wid = threadIdx.x >> 6, lane = threadIdx.x & 63;
    const int q = lane >> 4, nlo = lane & 15;
    const int n0 = blockIdx.y * 64 + wid * 16;
    const int m = mt * 16 + nlo;
    const size_t S = (size_t)NG * 1024;

    const float* ar = r1p + (size_t)m * 1024 + q * 8;
    const bf16_t* brow = wb2 + (size_t)(n0 + nlo) * 1024 + q * 8;
    f32x4 acc = {0.f, 0.f, 0.f, 0.f};

    for (int ch = 0; ch < 32; ++ch) {
        const int ko = ch * 32;
        float4 s0 = *(const float4*)(ar + ko);
        float4 s1 = *(const float4*)(ar + ko + 4);
#pragma unroll
        for (int sl = 1; sl < 8; ++sl) {
            const float4 t0 = *(const float4*)(ar + (size_t)sl * S + ko);
            const float4 t1 = *(const float4*)(ar + (size_t)sl * S + ko + 4);
            s0.x += t0.x; s0.y += t0.y; s0.z += t0.z; s0.w += t0.w;
            s1.x += t1.x; s1.y += t1.y; s1.z += t1.z; s1.w += t1.w;
        }
        const float4 bb0 = *(const float4*)(b1 + ko + q * 8);
        const float4 bb1 = *(const float4*)(b1 + ko + q * 8 + 4);
        bf16x8 a;
        a[0] = (bf16_t)fmaxf(s0.x + bb0.x, 0.f);
        a[1] = (bf16_t)fmaxf(s0.y + bb0.y, 0.f);
        a[2] = (bf16_t)fmaxf(s0.z + bb0.z, 0.f);
        a[3] = (bf16_t)fmaxf(s0.w + bb0.w, 0.f);
        a[4] = (bf16_t)fmaxf(s1.x + bb1.x, 0.f);
        a[5] = (bf16_t)fmaxf(s1.y + bb1.y, 0.f);
        a[6] = (bf16_t)fmaxf(s1.z + bb1.z, 0.f);
        a[7] = (bf16_t)fmaxf(s1.w + bb1.w, 0.f);
        const bf16x8 bv = *(const bf16x8*)(brow + ko);
        acc = __builtin_amdgcn_mfma_f32_16x16x32_bf16(a, bv, acc, 0, 0, 0);
    }
    const float bias = b2[n0 + nlo];
#pragma unroll
    for (int r = 0; r < 4; ++r)
        out[(size_t)(mt * 16 + q * 4 + r) * 512 + n0 + nlo] = acc[r] + bias;
}

// ---------------------------------------------------------------------------
extern "C" void kernel_launch(void* const* d_in, const int* in_sizes, int n_in,
                              void* d_out, int out_size, void* d_ws, size_t ws_size,
                              hipStream_t stream)
{
    const float* x0   = (const float*)d_in[0];
    const float* x1   = (const float*)d_in[1];
    const float* x2   = (const float*)d_in[2];
    const int*   ei0  = (const int*)d_in[3];
    const int*   ei1  = (const int*)d_in[4];
    const int*   ei2  = (const int*)d_in[5];
    const float* ea0  = (const float*)d_in[6];
    const float* ea1  = (const float*)d_in[7];
    const float* ea2  = (const float*)d_in[8];
    const float* gc1w = (const float*)d_in[9];
    const float* gc1b = (const float*)d_in[10];
    const float* gc4w = (const float*)d_in[11];
    const float* gc4b = (const float*)d_in[12];
    const float* fc1w = (const float*)d_in[13];
    const float* fc1b = (const float*)d_in[14];
    const float* fc2w = (const float*)d_in[15];
    const float* fc2b = (const float*)d_in[16];

    float*    ws   = (float*)d_ws;
    float*    xw0  = ws + XW0_OFF;
    bf16_t*   xw1b = (bf16_t*)(ws + XW1B_OFF);
    bf16_t*   wb   = (bf16_t*)(ws + WB_OFF);
    bf16_t*   wb2  = (bf16_t*)(ws + WB2_OFF);
    bf16_t*   wxt  = (bf16_t*)(ws + WXT_OFF);
    bf16_t*   hb   = (bf16_t*)(ws + HB_OFF);
    bf16_t*   h1g  = (bf16_t*)(ws + H1G_OFF);
    float*    L    = ws + L_OFF;
    float*    r1p  = ws + R1P_OFF;            // aliases L (dead after conv2)
    bf16_t*   fbp  = (bf16_t*)(ws + FB_OFF);  // aliases xw0 (dead after conv1)
    float*    out  = (float*)d_out;

    k_prep <<<NCASTB + NCASTB2 + LZB + 1, 256, 0, stream>>>(fc1w, fc2w, gc1w, wb, wb2, L, wxt);
    k_lb   <<<NG, 256, 0, stream>>>(ei0, ei1, ei2, ea0, ea1, ea2, L);
    k_xw   <<<dim3(5, NG), 256, 0, stream>>>(x0, x1, x2, wxt, xw0, xw1b);
    k_conv1<<<dim3(5, NG), 256, 0, stream>>>(L, xw0, xw1b, gc1b, gc4w, hb, h1g);
    k_conv2<<<dim3(5, NG), 256, 0, stream>>>(L, hb, h1g, gc4w, gc4b, fbp);
    k_fc1  <<<dim3(12, 4, 8), 256, 0, stream>>>(fbp, wb, r1p);
    k_fc2  <<<dim3(12, 8), 256, 0, stream>>>(r1p, fc1b, wb2, fc2b, out);
}

// Round 5
// 360.219 us; speedup vs baseline: 1.0788x; 1.0788x over previous
//
#include <hip/hip_runtime.h>

// Siamese GeoCheby, round 5: dense bf16 L built in LDS (no global atomics).
//  - k_lb: 5 row-chunks/graph; 54x288 fp32 chunk in LDS, LDS atomicAdd scatter,
//    bf16 writeout with zero-padded stride 288 (MFMA-ready rows).
//  - conv1/conv2: A operand = unconditional aligned bf16x8 loads from L.
//  - no L zero-fill; workspace 48 MB.

#define NN    268
#define EE    8576
#define NG    192
#define FDIM  4288       // 268*16
#define LSTR  288        // padded L row stride (bf16), 9 chunks * 32
#define CHUNK 54         // L rows per k_lb block (5 chunks cover 268)

typedef __bf16 bf16_t;
typedef bf16_t bf16x8 __attribute__((ext_vector_type(8)));
typedef bf16_t bf16x4 __attribute__((ext_vector_type(4)));
typedef float  f32x4  __attribute__((ext_vector_type(4)));

// ---- workspace layout (float32 slots, all %4==0 for 16B alignment) ----
#define XW0_OFF  0                    // 823296 f32; later reused as FB (bf16)
#define XW1B_OFF 823296               // 411648 f
#define WB_OFF   1234944              // 2195456 f
#define WB2_OFF  3430400              // 262144 f
#define WXT_OFF  3692544              // 4608 f
#define HB_OFF   3697152              // 411648 f
#define H1G_OFF  4108800              // 411648 f
#define LB_OFF   4520448              // 192*268*288 bf16 = 7409664 f; reused as R1P
#define WS_TOP   11930112             // 47.7 MB
#define R1P_OFF  LB_OFF               // 8*192*1024 = 1572864 f (L dead after conv2)
#define FB_OFF   XW0_OFF              // 192*4288 bf16 (xw0 dead after conv1)

#define NCASTB   2144                 // fc1w cast blocks
#define NCASTB2  256                  // fc2w cast blocks

// ---------------------------------------------------------------------------
// K0: cast fc1_w/fc2_w to bf16; build MFMA B-frags of [w0|w1]
// ---------------------------------------------------------------------------
__global__ __launch_bounds__(256) void k_prep(
    const float* __restrict__ fc1w, const float* __restrict__ fc2w,
    const float* __restrict__ gc1w,
    bf16_t* __restrict__ wb, bf16_t* __restrict__ wb2, bf16_t* __restrict__ wxt)
{
    const int bx = blockIdx.x;
    if (bx < NCASTB + NCASTB2) {
        const float* src; bf16_t* dst; size_t base;
        if (bx < NCASTB) { src = fc1w; dst = wb;  base = ((size_t)bx * 256 + threadIdx.x) * 8; }
        else             { src = fc2w; dst = wb2; base = ((size_t)(bx - NCASTB) * 256 + threadIdx.x) * 8; }
        const float4 a = *(const float4*)(src + base);
        const float4 b = *(const float4*)(src + base + 4);
        bf16x8 v;
        v[0] = (bf16_t)a.x; v[1] = (bf16_t)a.y; v[2] = (bf16_t)a.z; v[3] = (bf16_t)a.w;
        v[4] = (bf16_t)b.x; v[5] = (bf16_t)b.y; v[6] = (bf16_t)b.z; v[7] = (bf16_t)b.w;
        *(bf16x8*)(dst + base) = v;
    } else {
        // B-frag for 16x16x32: lane holds B[k=(lane>>4)*8+j][n=lane&15]; zero k>=268
        for (int idx = threadIdx.x; idx < 2 * 9 * 64; idx += 256) {
            const int lane = idx & 63, chunk = (idx >> 6) % 9, nt = idx / (9 * 64);
            const int n = lane & 15, q = lane >> 4;
            bf16x8 v;
#pragma unroll
            for (int j = 0; j < 8; ++j) {
                const int k = chunk * 32 + q * 8 + j;
                v[j] = (k < NN) ? (bf16_t)gc1w[nt * FDIM + k * 16 + n] : (bf16_t)0.f;
            }
            *(bf16x8*)(wxt + (size_t)idx * 8) = v;
        }
    }
}

// ---------------------------------------------------------------------------
// K1: dense bf16 L build, one 54-row chunk per block, all accumulation in LDS
// ---------------------------------------------------------------------------
__global__ __launch_bounds__(256) void k_lb(
    const int* __restrict__ ei0, const int* __restrict__ ei1, const int* __restrict__ ei2,
    const float* __restrict__ ea0, const float* __restrict__ ea1, const float* __restrict__ ea2,
    bf16_t* __restrict__ Lb)
{
    const int g = blockIdx.y;
    const int c0 = blockIdx.x * CHUNK;
    const int rows = (NN - c0 < CHUNK) ? (NN - c0) : CHUNK;
    const int br = g >> 6, b = g & 63;
    const int*   ei = (br == 0) ? ei0 : (br == 1) ? ei1 : ei2;
    const float* ea = (br == 0) ? ea0 : (br == 1) ? ea1 : ea2;
    const int*   rowp = ei + (size_t)b * (2 * EE);
    const int*   colp = rowp + EE;
    const float* eap  = ea + (size_t)b * EE;

    __shared__ float accS[CHUNK * LSTR];   // 62208 B
    __shared__ float degS[NN];             // 1072 B
    const int tid = threadIdx.x;

    {
        const float4 z = make_float4(0.f, 0.f, 0.f, 0.f);
        for (int i = tid; i < CHUNK * LSTR / 4; i += 256) ((float4*)accS)[i] = z;
        for (int n = tid; n < NN; n += 256) degS[n] = 0.f;
    }
    __syncthreads();
    for (int e = tid; e < EE; e += 256) atomicAdd(&degS[rowp[e]], eap[e]);
    __syncthreads();
    for (int n = tid; n < NN; n += 256) {
        const float d = degS[n];
        degS[n] = (d > 0.f) ? rsqrtf(d) : 0.f;
    }
    __syncthreads();
    for (int e = tid; e < EE; e += 256) {
        const int r = rowp[e];
        const int rr = r - c0;
        if ((unsigned)rr < (unsigned)rows) {
            const int c = colp[e];
            atomicAdd(&accS[rr * LSTR + c], -eap[e] * degS[r] * degS[c]);
        }
    }
    __syncthreads();
    // writeout: fp32 LDS -> bf16 global (rows contiguous, pads are zero)
    bf16_t* dst = Lb + ((size_t)g * NN + c0) * LSTR;
    const int tot = rows * LSTR;             // multiple of 8
    for (int i = tid * 8; i < tot; i += 256 * 8) {
        const float4 a = *(const float4*)&accS[i];
        const float4 b2 = *(const float4*)&accS[i + 4];
        bf16x8 v;
        v[0] = (bf16_t)a.x;  v[1] = (bf16_t)a.y;  v[2] = (bf16_t)a.z;  v[3] = (bf16_t)a.w;
        v[4] = (bf16_t)b2.x; v[5] = (bf16_t)b2.y; v[6] = (bf16_t)b2.z; v[7] = (bf16_t)b2.w;
        *(bf16x8*)(dst + i) = v;
    }
}

// ---------------------------------------------------------------------------
// K2: xw = x @ [w0|w1] via MFMA (4 waves/block, wave = one 16-row tile)
// ---------------------------------------------------------------------------
__global__ __launch_bounds__(256) void k_xw(
    const float* __restrict__ x0, const float* __restrict__ x1, const float* __restrict__ x2,
    const bf16_t* __restrict__ wxt, float* __restrict__ xw0, bf16_t* __restrict__ xw1b)
{
    const int g = blockIdx.y;
    const int br = g >> 6, b = g & 63;
    const float* x = ((br == 0) ? x0 : (br == 1) ? x1 : x2) + (size_t)b * (NN * NN);
    const int wave = threadIdx.x >> 6, lane = threadIdx.x & 63;
    const int tile = blockIdx.x * 4 + wave;
    if (tile >= 17) return;
    const int q = lane >> 4, nlo = lane & 15;
    const int mrow = tile * 16 + nlo;
    const int mclamp = (mrow < NN) ? mrow : (NN - 1);    // garbage rows never stored
    const float* xrow = x + (size_t)mclamp * NN;

    f32x4 acc0 = {0.f, 0.f, 0.f, 0.f}, acc1 = {0.f, 0.f, 0.f, 0.f};
#pragma unroll
    for (int ch = 0; ch < 9; ++ch) {
        const int k0 = ch * 32 + q * 8;
        float4 p0 = make_float4(0.f, 0.f, 0.f, 0.f);
        float4 p1 = make_float4(0.f, 0.f, 0.f, 0.f);
        if (ch < 8) {                 // k0+8 <= 256 < 268: always safe
            p0 = *(const float4*)(xrow + k0);
            p1 = *(const float4*)(xrow + k0 + 4);
        } else {                      // tail chunk: guard per quarter
            if (k0 + 4 <= NN) p0 = *(const float4*)(xrow + k0);
            if (k0 + 8 <= NN) p1 = *(const float4*)(xrow + k0 + 4);
        }
        bf16x8 a;
        a[0] = (bf16_t)p0.x; a[1] = (bf16_t)p0.y; a[2] = (bf16_t)p0.z; a[3] = (bf16_t)p0.w;
        a[4] = (bf16_t)p1.x; a[5] = (bf16_t)p1.y; a[6] = (bf16_t)p1.z; a[7] = (bf16_t)p1.w;
        const bf16x8 b0 = *(const bf16x8*)(wxt + (size_t)(ch * 64 + lane) * 8);
        const bf16x8 b1 = *(const bf16x8*)(wxt + (size_t)(576 + ch * 64 + lane) * 8);
        acc0 = __builtin_amdgcn_mfma_f32_16x16x32_bf16(a, b0, acc0, 0, 0, 0);
        acc1 = __builtin_amdgcn_mfma_f32_16x16x32_bf16(a, b1, acc1, 0, 0, 0);
    }
#pragma unroll
    for (int r = 0; r < 4; ++r) {
        const int row = tile * 16 + q * 4 + r;
        if (row < NN) {
            xw0[((size_t)g * NN + row) * 16 + nlo]  = acc0[r];
            xw1b[((size_t)g * NN + row) * 16 + nlo] = (bf16_t)acc1[r];
        }
    }
}

// ---------------------------------------------------------------------------
// K3: conv1: h = relu(xw0 + L@xw1 + b1) -> hb; epilogue H1 = h@w4_1 -> h1g
// ---------------------------------------------------------------------------
__global__ __launch_bounds__(256) void k_conv1(
    const bf16_t* __restrict__ Lb, const float* __restrict__ xw0,
    const bf16_t* __restrict__ xw1b, const float* __restrict__ gc1b,
    const float* __restrict__ gc4w, bf16_t* __restrict__ hb, bf16_t* __restrict__ h1g)
{
    const int g = blockIdx.y;
    const int tid = threadIdx.x;
    const int wave = tid >> 6, lane = tid & 63;
    const int tile = blockIdx.x * 4 + wave;
    const int q = lane >> 4, nlo = lane & 15;
    const int blk0 = blockIdx.x * 64;

    __shared__ __align__(16) bf16_t x1_s[NN * 16];      // 8.6 KB
    __shared__ __align__(16) bf16_t frag_s[9 * 64 * 8]; // 9.2 KB
    __shared__ float h_s[64 * 17];                      // 4.3 KB
    __shared__ float w41_s[256];
    __shared__ float b1_s[16];

    {
        const bf16x8* src = (const bf16x8*)(xw1b + (size_t)g * FDIM);
        for (int i = tid; i < FDIM / 8; i += 256) ((bf16x8*)x1_s)[i] = src[i];
    }
    if (tid < 256) w41_s[tid] = gc4w[256 + tid];
    if (tid < 16) b1_s[tid] = gc1b[tid];
    __syncthreads();
    for (int it = tid; it < 576; it += 256) {
        const int fl = it & 63, ch = it >> 6;
        const int fn = fl & 15, fq = fl >> 4;
        bf16x8 v;
#pragma unroll
        for (int j = 0; j < 8; ++j) {
            const int k = ch * 32 + fq * 8 + j;
            v[j] = (k < NN) ? x1_s[k * 16 + fn] : (bf16_t)0.f;
        }
        *(bf16x8*)(frag_s + (size_t)it * 8) = v;
    }
    __syncthreads();

    if (tile < 17) {
        const int m = tile * 16 + nlo;
        const int mc = (m < NN) ? m : (NN - 1);
        const bf16_t* lrow = Lb + ((size_t)g * NN + mc) * LSTR + q * 8;
        f32x4 acc = {0.f, 0.f, 0.f, 0.f};
#pragma unroll
        for (int ch = 0; ch < 9; ++ch) {
            const bf16x8 a = *(const bf16x8*)(lrow + ch * 32);
            const bf16x8 bv = *(const bf16x8*)(frag_s + (size_t)(ch * 64 + lane) * 8);
            acc = __builtin_amdgcn_mfma_f32_16x16x32_bf16(a, bv, acc, 0, 0, 0);
        }
#pragma unroll
        for (int r = 0; r < 4; ++r) {
            const int row = tile * 16 + q * 4 + r;
            if (row < NN) {
                float v = acc[r] + xw0[((size_t)g * NN + row) * 16 + nlo] + b1_s[nlo];
                v = fmaxf(v, 0.f);
                hb[((size_t)g * NN + row) * 16 + nlo] = (bf16_t)v;
                h_s[(row - blk0) * 17 + nlo] = v;
            }
        }
    }
    __syncthreads();

    // H1 = h @ w4[1] for this block's 64 rows
    {
        const int m = tid >> 2, jb = tid & 3;
        const int row = blk0 + m;
        if (row < NN) {
            float4 a = make_float4(0.f, 0.f, 0.f, 0.f);
#pragma unroll
            for (int k = 0; k < 16; ++k) {
                const float hv = h_s[m * 17 + k];
                const float4 w = *(const float4*)&w41_s[k * 16 + jb * 4];
                a.x += hv * w.x; a.y += hv * w.y; a.z += hv * w.z; a.w += hv * w.w;
            }
            bf16x4 o;
            o[0] = (bf16_t)a.x; o[1] = (bf16_t)a.y; o[2] = (bf16_t)a.z; o[3] = (bf16_t)a.w;
            *(bf16x4*)(h1g + ((size_t)g * NN + row) * 16 + jb * 4) = o;
        }
    }
}

// ---------------------------------------------------------------------------
// K4: conv2: f = h@w4_0 + b4 + L@H1 -> fb (bf16)
// ---------------------------------------------------------------------------
__global__ __launch_bounds__(256) void k_conv2(
    const bf16_t* __restrict__ Lb, const bf16_t* __restrict__ hb,
    const bf16_t* __restrict__ h1g, const float* __restrict__ gc4w,
    const float* __restrict__ gc4b, bf16_t* __restrict__ fb)
{
    const int g = blockIdx.y;
    const int tid = threadIdx.x;
    const int wave = tid >> 6, lane = tid & 63;
    const int tile = blockIdx.x * 4 + wave;
    const int q = lane >> 4, nlo = lane & 15;

    __shared__ __align__(16) bf16_t h1_s[NN * 16];
    __shared__ __align__(16) bf16_t frag_s[9 * 64 * 8];
    __shared__ float w40_s[256];
    __shared__ float b4_s[16];

    {
        const bf16x8* src = (const bf16x8*)(h1g + (size_t)g * FDIM);
        for (int i = tid; i < FDIM / 8; i += 256) ((bf16x8*)h1_s)[i] = src[i];
    }
    if (tid < 256) w40_s[tid] = gc4w[tid];
    if (tid < 16) b4_s[tid] = gc4b[tid];
    __syncthreads();
    for (int it = tid; it < 576; it += 256) {
        const int fl = it & 63, ch = it >> 6;
        const int fn = fl & 15, fq = fl >> 4;
        bf16x8 v;
#pragma unroll
        for (int j = 0; j < 8; ++j) {
            const int k = ch * 32 + fq * 8 + j;
            v[j] = (k < NN) ? h1_s[k * 16 + fn] : (bf16_t)0.f;
        }
        *(bf16x8*)(frag_s + (size_t)it * 8) = v;
    }
    __syncthreads();

    if (tile >= 17) return;
    const int m = tile * 16 + nlo;
    const int mc = (m < NN) ? m : (NN - 1);
    const bf16_t* lrow = Lb + ((size_t)g * NN + mc) * LSTR + q * 8;
    f32x4 acc = {0.f, 0.f, 0.f, 0.f};
#pragma unroll
    for (int ch = 0; ch < 9; ++ch) {
        const bf16x8 a = *(const bf16x8*)(lrow + ch * 32);
        const bf16x8 bv = *(const bf16x8*)(frag_s + (size_t)(ch * 64 + lane) * 8);
        acc = __builtin_amdgcn_mfma_f32_16x16x32_bf16(a, bv, acc, 0, 0, 0);
    }
    float w40col[16];
#pragma unroll
    for (int k = 0; k < 16; ++k) w40col[k] = w40_s[k * 16 + nlo];
#pragma unroll
    for (int r = 0; r < 4; ++r) {
        const int row = tile * 16 + q * 4 + r;
        if (row < NN) {
            const bf16x8 h0 = *(const bf16x8*)(hb + ((size_t)g * NN + row) * 16);
            const bf16x8 h1 = *(const bf16x8*)(hb + ((size_t)g * NN + row) * 16 + 8);
            float s = acc[r] + b4_s[nlo];
#pragma unroll
            for (int k = 0; k < 8; ++k) s += (float)h0[k] * w40col[k];
#pragma unroll
            for (int k = 0; k < 8; ++k) s += (float)h1[k] * w40col[8 + k];
            fb[((size_t)g * NN + row) * 16 + nlo] = (bf16_t)s;
        }
    }
}

// ---------------------------------------------------------------------------
// K5: fc1 MFMA split-K8: r1p[kz][192][1024] = fb @ wb^T
// ---------------------------------------------------------------------------
__global__ __launch_bounds__(256) void k_fc1(
    const bf16_t* __restrict__ fb, const bf16_t* __restrict__ wb, float* __restrict__ r1p)
{
    const int mt = blockIdx.x, nb = blockIdx.y, kz = blockIdx.z;
    const int wid = threadIdx.x >> 6, lane = threadIdx.x & 63;
    const int q = lane >> 4, nlo = lane & 15;
    const int n0 = nb * 256 + wid * 64;
    const int cstart = (kz < 6) ? kz * 17 : 102 + (kz - 6) * 16;
    const int ccnt   = (kz < 6) ? 17 : 16;

    const bf16_t* arow = fb + (size_t)(mt * 16 + nlo) * FDIM + q * 8;
    const bf16_t* brow = wb + (size_t)(n0 + nlo) * FDIM + q * 8;
    f32x4 acc[4];
#pragma unroll
    for (int t = 0; t < 4; ++t) { acc[t][0]=0.f; acc[t][1]=0.f; acc[t][2]=0.f; acc[t][3]=0.f; }

    for (int ch = 0; ch < ccnt; ++ch) {
        const size_t ko = (size_t)(cstart + ch) * 32;
        const bf16x8 a = *(const bf16x8*)(arow + ko);
#pragma unroll
        for (int t = 0; t < 4; ++t) {
            const bf16x8 bv = *(const bf16x8*)(brow + (size_t)t * 16 * FDIM + ko);
            acc[t] = __builtin_amdgcn_mfma_f32_16x16x32_bf16(a, bv, acc[t], 0, 0, 0);
        }
    }
    float* outp = r1p + (size_t)kz * (NG * 1024);
#pragma unroll
    for (int t = 0; t < 4; ++t)
#pragma unroll
        for (int r = 0; r < 4; ++r)
            outp[(size_t)(mt * 16 + q * 4 + r) * 1024 + n0 + t * 16 + nlo] = acc[t][r];
}

// ---------------------------------------------------------------------------
// K6: fc2 fused: out = relu(sum_kz r1p + fc1_b) @ wb2^T + fc2_b
// ---------------------------------------------------------------------------
__global__ __launch_bounds__(256) void k_fc2(
    const float* __restrict__ r1p, const float* __restrict__ b1,
    const bf16_t* __restrict__ wb2, const float* __restrict__ b2,
    float* __restrict__ out)
{
    const int mt = blockIdx.x;
    const int wid = threadIdx.x >> 6, lane = threadIdx.x & 63;
    const int q = lane >> 4, nlo = lane & 15;
    const int n0 = blockIdx.y * 64 + wid * 16;
    const int m = mt * 16 + nlo;
    const size_t S = (size_t)NG * 1024;

    const float* ar = r1p + (size_t)m * 1024 + q * 8;
    const bf16_t* brow = wb2 + (size_t)(n0 + nlo) * 1024 + q * 8;
    f32x4 acc = {0.f, 0.f, 0.f, 0.f};

    for (int ch = 0; ch < 32; ++ch) {
        const int ko = ch * 32;
        float4 s0 = *(const float4*)(ar + ko);
        float4 s1 = *(const float4*)(ar + ko + 4);
#pragma unroll
        for (int sl = 1; sl < 8; ++sl) {
            const float4 t0 = *(const float4*)(ar + (size_t)sl * S + ko);
            const float4 t1 = *(const float4*)(ar + (size_t)sl * S + ko + 4);
            s0.x += t0.x; s0.y += t0.y; s0.z += t0.z; s0.w += t0.w;
            s1.x += t1.x; s1.y += t1.y; s1.z += t1.z; s1.w += t1.w;
        }
        const float4 bb0 = *(const float4*)(b1 + ko + q * 8);
        const float4 bb1 = *(const float4*)(b1 + ko + q * 8 + 4);
        bf16x8 a;
        a[0] = (bf16_t)fmaxf(s0.x + bb0.x, 0.f);
        a[1] = (bf16_t)fmaxf(s0.y + bb0.y, 0.f);
        a[2] = (bf16_t)fmaxf(s0.z + bb0.z, 0.f);
        a[3] = (bf16_t)fmaxf(s0.w + bb0.w, 0.f);
        a[4] = (bf16_t)fmaxf(s1.x + bb1.x, 0.f);
        a[5] = (bf16_t)fmaxf(s1.y + bb1.y, 0.f);
        a[6] = (bf16_t)fmaxf(s1.z + bb1.z, 0.f);
        a[7] = (bf16_t)fmaxf(s1.w + bb1.w, 0.f);
        const bf16x8 bv = *(const bf16x8*)(brow + ko);
        acc = __builtin_amdgcn_mfma_f32_16x16x32_bf16(a, bv, acc, 0, 0, 0);
    }
    const float bias = b2[n0 + nlo];
#pragma unroll
    for (int r = 0; r < 4; ++r)
        out[(size_t)(mt * 16 + q * 4 + r) * 512 + n0 + nlo] = acc[r] + bias;
}

// ---------------------------------------------------------------------------
extern "C" void kernel_launch(void* const* d_in, const int* in_sizes, int n_in,
                              void* d_out, int out_size, void* d_ws, size_t ws_size,
                              hipStream_t stream)
{
    const float* x0   = (const float*)d_in[0];
    const float* x1   = (const float*)d_in[1];
    const float* x2   = (const float*)d_in[2];
    const int*   ei0  = (const int*)d_in[3];
    const int*   ei1  = (const int*)d_in[4];
    const int*   ei2  = (const int*)d_in[5];
    const float* ea0  = (const float*)d_in[6];
    const float* ea1  = (const float*)d_in[7];
    const float* ea2  = (const float*)d_in[8];
    const float* gc1w = (const float*)d_in[9];
    const float* gc1b = (const float*)d_in[10];
    const float* gc4w = (const float*)d_in[11];
    const float* gc4b = (const float*)d_in[12];
    const float* fc1w = (const float*)d_in[13];
    const float* fc1b = (const float*)d_in[14];
    const float* fc2w = (const float*)d_in[15];
    const float* fc2b = (const float*)d_in[16];

    float*    ws   = (float*)d_ws;
    float*    xw0  = ws + XW0_OFF;
    bf16_t*   xw1b = (bf16_t*)(ws + XW1B_OFF);
    bf16_t*   wb   = (bf16_t*)(ws + WB_OFF);
    bf16_t*   wb2  = (bf16_t*)(ws + WB2_OFF);
    bf16_t*   wxt  = (bf16_t*)(ws + WXT_OFF);
    bf16_t*   hb   = (bf16_t*)(ws + HB_OFF);
    bf16_t*   h1g  = (bf16_t*)(ws + H1G_OFF);
    bf16_t*   Lb   = (bf16_t*)(ws + LB_OFF);
    float*    r1p  = ws + R1P_OFF;            // aliases Lb (dead after conv2)
    bf16_t*   fbp  = (bf16_t*)(ws + FB_OFF);  // aliases xw0 (dead after conv1)
    float*    out  = (float*)d_out;

    k_prep <<<NCASTB + NCASTB2 + 1, 256, 0, stream>>>(fc1w, fc2w, gc1w, wb, wb2, wxt);
    k_lb   <<<dim3(5, NG), 256, 0, stream>>>(ei0, ei1, ei2, ea0, ea1, ea2, Lb);
    k_xw   <<<dim3(5, NG), 256, 0, stream>>>(x0, x1, x2, wxt, xw0, xw1b);
    k_conv1<<<dim3(5, NG), 256, 0, stream>>>(Lb, xw0, xw1b, gc1b, gc4w, hb, h1g);
    k_conv2<<<dim3(5, NG), 256, 0, stream>>>(Lb, hb, h1g, gc4w, gc4b, fbp);
    k_fc1  <<<dim3(12, 4, 8), 256, 0, stream>>>(fbp, wb, r1p);
    k_fc2  <<<dim3(12, 8), 256, 0, stream>>>(r1p, fc1b, wb2, fc2b, out);
}